// Round 9
// baseline (645.719 us; speedup 1.0000x reference)
//
#include <hip/hip_runtime.h>
#include <hip/hip_bf16.h>
#include <math.h>

#define D_MODEL 1024
#define D_FF    4096
#define NEXP    8
#define NTOK    4096
#define NROUTED 8192
#define MAXJOBS 40

typedef __attribute__((ext_vector_type(8))) short bf16x8;
typedef __attribute__((ext_vector_type(4))) float f32x4;
typedef __attribute__((ext_vector_type(4))) unsigned short us4;

// ---- workspace byte offsets ----
#define WS_CNT   0                         // int[8]
#define WS_CNT2  64                        // int[8]
#define WS_OFF   128                       // int[9]
#define WS_JOBS  192                       // int[1+MAXJOBS]
#define WS_TI    512                       // int[NTOK*2]
#define WS_TW    (WS_TI + NTOK*2*4)        // float[NTOK*2]
#define WS_TOK   (WS_TW + NTOK*2*4)        // int[NROUTED]
#define WS_GWT   (WS_TOK + NROUTED*4)      // float[NROUTED]
#define WS_XG    (((WS_GWT + NROUTED*4) + 255) & ~255)       // bf16[NROUTED][1024]  (16 MB)
#define WS_H     (WS_XG + (size_t)NROUTED*D_MODEL*2)         // bf16[NROUTED][4096]  (64 MB)
#define WS_WT    (WS_H + (size_t)NROUTED*D_FF*2)             // bf16[E][F][K] shared (64 MB)
// total ~144 MB

__device__ __forceinline__ unsigned short f2bf(float f){
  union { float f; unsigned u; } a; a.f = f;
  unsigned u = a.u;
  u = u + 0x7FFF + ((u >> 16) & 1);   // RNE
  return (unsigned short)(u >> 16);
}

__device__ __forceinline__ void gload_lds16(const void* g, void* l){
  __builtin_amdgcn_global_load_lds((const __attribute__((address_space(1))) void*)g,
                                   (__attribute__((address_space(3))) void*)l, 16, 0, 0);
}

// ---------------- gating ----------------
__global__ void moe_gate_kernel(const float* __restrict__ x, const float* __restrict__ gw,
                                int* cnt, int* __restrict__ ti, float* __restrict__ tw){
  int n = blockIdx.x*4 + (threadIdx.x >> 6);
  int lane = threadIdx.x & 63;
  const float* xr = x + (size_t)n * D_MODEL;
  float acc[NEXP];
  #pragma unroll
  for (int e=0;e<NEXP;e++) acc[e] = 0.f;
  for (int d=lane; d<D_MODEL; d+=64){
    float xv = xr[d];
    #pragma unroll
    for (int e=0;e<NEXP;e++) acc[e] += xv * gw[d*NEXP + e];
  }
  #pragma unroll
  for (int e=0;e<NEXP;e++){
    #pragma unroll
    for (int o=32;o;o>>=1) acc[e] += __shfl_down(acc[e], o, 64);
  }
  if (lane == 0){
    int i0 = 0; float v0 = acc[0];
    #pragma unroll
    for (int e=1;e<NEXP;e++) if (acc[e] > v0){ v0 = acc[e]; i0 = e; }
    int i1 = -1; float v1 = -1e30f;
    #pragma unroll
    for (int e=0;e<NEXP;e++) if (e != i0 && acc[e] > v1){ v1 = acc[e]; i1 = e; }
    float p = expf(v1 - v0);
    float inv = 1.f / (1.f + p);
    ti[n*2] = i0; ti[n*2+1] = i1;
    tw[n*2] = inv; tw[n*2+1] = p * inv;
    atomicAdd(&cnt[i0], 1); atomicAdd(&cnt[i1], 1);
  }
}

// prefix sums + job list (job = one 256-row stripe of one expert)
__global__ void moe_prefix_kernel(const int* __restrict__ cnt, int* __restrict__ off,
                                  int* __restrict__ jobs){
  if (threadIdx.x == 0){
    int s = 0;
    for (int e=0;e<NEXP;e++){ off[e] = s; s += cnt[e]; }
    off[NEXP] = s;
    int idx = 0;
    for (int e=0;e<NEXP;e++){
      int ns = (cnt[e] + 255) >> 8;
      for (int q=0;q<ns;q++) jobs[1+idx++] = (e<<16) | q;
    }
    jobs[0] = idx;
  }
}

__global__ void moe_assign_kernel(const float* __restrict__ x, const int* __restrict__ ti,
                                  const float* __restrict__ tw, const int* __restrict__ off,
                                  int* cnt2, int* __restrict__ tok, float* __restrict__ gwt,
                                  unsigned short* __restrict__ Xg){
  __shared__ int ss[2];
  int n = blockIdx.x;
  if (threadIdx.x == 0){
    int i0 = ti[n*2], i1 = ti[n*2+1];
    int s0 = off[i0] + atomicAdd(&cnt2[i0], 1);
    int s1 = off[i1] + atomicAdd(&cnt2[i1], 1);
    tok[s0] = n; tok[s1] = n;
    gwt[s0] = tw[n*2]; gwt[s1] = tw[n*2+1];
    ss[0] = s0; ss[1] = s1;
  }
  __syncthreads();
  int s0 = ss[0], s1 = ss[1];
  int t = threadIdx.x;
  float4 v = ((const float4*)(x + (size_t)n * D_MODEL))[t];
  us4 pk = { f2bf(v.x), f2bf(v.y), f2bf(v.z), f2bf(v.w) };
  *(us4*)(Xg + (size_t)s0 * D_MODEL + t*4) = pk;
  *(us4*)(Xg + (size_t)s1 * D_MODEL + t*4) = pk;
}

// ---------------- weight transpose + bf16 convert: W(E,K,F) f32 -> Wt(E,F,K) bf16 ----------------
__global__ __launch_bounds__(256) void transpose_bf16_kernel(
    const float* __restrict__ W, unsigned short* __restrict__ Wt, int K, int F){
  __shared__ float tile[64][65];
  int e = blockIdx.z;
  int f0 = blockIdx.x * 64, k0 = blockIdx.y * 64;
  const float* Wb = W + (size_t)e * K * F;
  unsigned short* Wtb = Wt + (size_t)e * F * K;
  int tid = threadIdx.x;
  #pragma unroll
  for (int i=0;i<4;i++){
    int idx = i*256 + tid;
    int r = idx >> 4, c4 = (idx & 15) * 4;
    float4 v = *(const float4*)(Wb + (size_t)(k0 + r) * F + f0 + c4);
    tile[r][c4] = v.x; tile[r][c4+1] = v.y; tile[r][c4+2] = v.z; tile[r][c4+3] = v.w;
  }
  __syncthreads();
  #pragma unroll
  for (int i=0;i<4;i++){
    int idx = i*256 + tid;
    int f = idx >> 4, k4 = (idx & 15) * 4;
    us4 pk = { f2bf(tile[k4][f]), f2bf(tile[k4+1][f]), f2bf(tile[k4+2][f]), f2bf(tile[k4+3][f]) };
    *(us4*)(Wtb + (size_t)(f0 + f) * K + k0 + k4) = pk;
  }
}

// ---------------- GEMM: 256x256, BK=64, 8 waves (512 thr), dbuf, compiler-scheduled inner ----------------
// MODE 1: Xg@W1t^T -> gelu -> H      (K=1024, 16 steps; grid.x = 16 col-tiles)
// MODE 2: H@W2t^T *g -> atomic out   (K=4096 split 4-way; grid.x = (kchunk<<2)|col; 16 steps)
// Per wave-step: 24 ds_read_b128 + 64 MFMA, NO pinning asm inside -> hipcc interleaves
// with counted lgkmcnt. Counted vmcnt + raw s_barrier only at step boundary (r5 skeleton).
// Swizzle: 16B chunk p at LDS row r holds global chunk p ^ (r&7)  (reads measured conflict-free).
template<int MODE>
__global__ __launch_bounds__(512, 2) void moe_gemm_kernel(
    char* __restrict__ wsb, const unsigned short* __restrict__ Bt,
    const float* __restrict__ bias, float* __restrict__ out)
{
  const int* jobs = (const int*)(wsb + WS_JOBS);
  if ((int)blockIdx.y >= jobs[0]) return;
  const int jb = jobs[1 + blockIdx.y];
  const int e = jb >> 16;
  const int row0 = (jb & 0xffff) << 8;

  const int* off = (const int*)(wsb + WS_OFF);
  const int n0 = off[e];
  const int ne = off[e+1] - n0;

  constexpr int K  = (MODE==1) ? D_MODEL : D_FF;
  constexpr int NT = 16;
  const int bx     = (MODE==1) ? blockIdx.x : (blockIdx.x & 3);
  const int kchunk = (MODE==1) ? 0 : (blockIdx.x >> 2);
  const int n_off  = bx * 256;
  const size_t kcb = (size_t)kchunk * 2048;       // byte offset of 1024-wide K-chunk

  const unsigned short* Ag  = (const unsigned short*)(wsb + (MODE==1 ? (size_t)WS_XG : (size_t)WS_H));
  const unsigned short* Bgt = Bt + (size_t)e * D_FF * D_MODEL;

  __shared__ __align__(16) char lds[2*65536];     // dbuf: [buf][ A 32KB | B 32KB ]

  const int tid = threadIdx.x, lane = tid & 63, w = tid >> 6;
  const int wr = w >> 2, wc = w & 3;              // 2x4 wave grid; wave tile 128 x 64

  // ---- staging: 8 gload_lds16 per thread per step (4 A-rowgroups + 4 B-rowgroups) ----
  const int arow   = lane >> 3;
  const int achunk = ((lane & 7) ^ arow) << 4;    // pre-swizzled 16B source chunk
  const char* aP[4]; const char* bP[4];
  #pragma unroll
  for (int i=0;i<4;i++){
    int r = (w*4 + i)*8 + arow;                   // 0..255
    int gr = row0 + r; if (gr >= ne) gr = ne - 1;
    aP[i] = (const char*)(Ag + (size_t)(n0 + gr) * K) + kcb + achunk;
    bP[i] = (const char*)(Bgt + (size_t)(n_off + r) * K) + kcb + achunk;
  }
  const int dstA = w*4096;                        // wave-uniform LDS dest bases

  f32x4 acc[8][4];
  #pragma unroll
  for (int i=0;i<8;i++)
    #pragma unroll
    for (int j=0;j<4;j++) acc[i][j] = (f32x4){0.f,0.f,0.f,0.f};

  #define STAGE(tt, bb) { \
    size_t kb = (size_t)(tt)*128; \
    char* d = lds + (bb)*65536 + dstA; \
    _Pragma("unroll") \
    for (int i=0;i<4;i++){ \
      gload_lds16(aP[i] + kb, d + i*1024); \
      gload_lds16(bP[i] + kb, d + 32768 + i*1024); \
    } }

  STAGE(0, 0);
  asm volatile("s_waitcnt vmcnt(0)" ::: "memory");
  __builtin_amdgcn_s_barrier();

  int cur = 0;
  for (int t = 0; t < NT; ++t){
    if (t + 1 < NT) STAGE(t + 1, cur ^ 1);        // prefetch next tile first

    const char* base = lds + cur*65536;
    const int q16 = (lane >> 4) << 4;             // q0*16
    // ---- plain C++ reads + MFMA: compiler interleaves with counted lgkmcnt ----
    #pragma unroll
    for (int kk=0; kk<2; ++kk){
      bf16x8 a[8], b[4];
      #pragma unroll
      for (int mi=0; mi<8; mi++){
        int row = wr*128 + mi*16 + (lane&15);
        a[mi] = *(const bf16x8*)(base + (row<<7) + (((kk<<6) + q16) ^ ((row&7)<<4)));
      }
      #pragma unroll
      for (int ni=0; ni<4; ni++){
        int col = wc*64 + ni*16 + (lane&15);
        b[ni] = *(const bf16x8*)(base + 32768 + (col<<7) + (((kk<<6) + q16) ^ ((col&7)<<4)));
      }
      #pragma unroll
      for (int ni=0; ni<4; ni++)
        #pragma unroll
        for (int mi=0; mi<8; mi++)
          acc[mi][ni] = __builtin_amdgcn_mfma_f32_16x16x32_bf16(a[mi], b[ni], acc[mi][ni], 0, 0, 0);
    }

    if (t + 1 < NT) asm volatile("s_waitcnt vmcnt(0)" ::: "memory");  // prefetch landed (covered by compute)
    __builtin_amdgcn_s_barrier();
    cur ^= 1;
  }
  #undef STAGE

  // ---- epilogue (wave tile 128 x 64) ----
  if (MODE == 1){
    const float* b1 = bias + (size_t)e * D_FF;
    unsigned short* H = (unsigned short*)(wsb + (size_t)WS_H);
    #pragma unroll
    for (int mi=0; mi<8; mi++){
      int rbase = wr*128 + mi*16 + ((lane>>4)<<2);
      #pragma unroll
      for (int rr=0;rr<4;rr++){
        int lrow = rbase + rr;
        if (row0 + lrow < ne){
          size_t hb = (size_t)(n0 + row0 + lrow) * D_FF;
          #pragma unroll
          for (int ni=0; ni<4; ni++){
            int gcol = n_off + wc*64 + ni*16 + (lane&15);
            float v = acc[mi][ni][rr] + b1[gcol];
            v = 0.5f * v * (1.f + erff(v * 0.70710678118654752f));
            H[hb + gcol] = f2bf(v);
          }
        }
      }
    }
  } else {
    const float* b2 = bias + (size_t)e * D_MODEL;
    const int* tok = (const int*)(wsb + WS_TOK);
    const float* gwt = (const float*)(wsb + WS_GWT);
    #pragma unroll
    for (int mi=0; mi<8; mi++){
      int rbase = wr*128 + mi*16 + ((lane>>4)<<2);
      #pragma unroll
      for (int rr=0;rr<4;rr++){
        int lrow = rbase + rr;
        if (row0 + lrow < ne){
          int slot = n0 + row0 + lrow;
          int tk = tok[slot];
          float g = gwt[slot];
          float* orow = out + (size_t)tk * D_MODEL;
          #pragma unroll
          for (int ni=0; ni<4; ni++){
            int gcol = n_off + wc*64 + ni*16 + (lane&15);
            float bb = (kchunk == 0) ? b2[gcol] : 0.f;
            atomicAdd(orow + gcol, (acc[mi][ni][rr] + bb) * g);
          }
        }
      }
    }
  }
}

extern "C" void kernel_launch(void* const* d_in, const int* in_sizes, int n_in,
                              void* d_out, int out_size, void* d_ws, size_t ws_size,
                              hipStream_t stream){
  const float* x   = (const float*)d_in[0];
  const float* gw  = (const float*)d_in[1];
  const float* w1  = (const float*)d_in[2];
  const float* b1  = (const float*)d_in[3];
  const float* w2  = (const float*)d_in[4];
  const float* b2  = (const float*)d_in[5];
  float* out = (float*)d_out;
  char* ws = (char*)d_ws;
  unsigned short* Wt = (unsigned short*)(ws + (size_t)WS_WT);

  hipMemsetAsync(ws, 0, 512, stream);                                   // counters + jobs
  hipMemsetAsync(out, 0, (size_t)NTOK * D_MODEL * sizeof(float), stream);

  moe_gate_kernel<<<NTOK/4, 256, 0, stream>>>(x, gw, (int*)(ws+WS_CNT),
                                              (int*)(ws+WS_TI), (float*)(ws+WS_TW));
  moe_prefix_kernel<<<1, 64, 0, stream>>>((const int*)(ws+WS_CNT), (int*)(ws+WS_OFF),
                                          (int*)(ws+WS_JOBS));
  moe_assign_kernel<<<NTOK, 256, 0, stream>>>(x, (const int*)(ws+WS_TI),
                                              (const float*)(ws+WS_TW), (const int*)(ws+WS_OFF),
                                              (int*)(ws+WS_CNT2), (int*)(ws+WS_TOK),
                                              (float*)(ws+WS_GWT),
                                              (unsigned short*)(ws + (size_t)WS_XG));
  // W1 (E,1024,4096) f32 -> Wt (E,4096,1024) bf16 ; then GEMM1
  transpose_bf16_kernel<<<dim3(D_FF/64, D_MODEL/64, NEXP), 256, 0, stream>>>(w1, Wt, D_MODEL, D_FF);
  moe_gemm_kernel<1><<<dim3(D_FF/256, MAXJOBS), 512, 0, stream>>>(ws, Wt, b1, out);
  // W2 (E,4096,1024) f32 -> Wt (E,1024,4096) bf16 ; then GEMM2 (K split 4-way)
  transpose_bf16_kernel<<<dim3(D_MODEL/64, D_FF/64, NEXP), 256, 0, stream>>>(w2, Wt, D_FF, D_MODEL);
  moe_gemm_kernel<2><<<dim3((D_MODEL/256)*4, MAXJOBS), 512, 0, stream>>>(ws, Wt, b2, out);
}

// Round 11
// 570.781 us; speedup vs baseline: 1.1313x; 1.1313x over previous
//
#include <hip/hip_runtime.h>
#include <hip/hip_bf16.h>
#include <math.h>

#define D_MODEL 1024
#define D_FF    4096
#define NEXP    8
#define NTOK    4096
#define NROUTED 8192
#define MAXJOBS 40

typedef __attribute__((ext_vector_type(8))) short bf16x8;
typedef __attribute__((ext_vector_type(4))) float f32x4;
typedef __attribute__((ext_vector_type(4))) unsigned short us4;

// ---- workspace byte offsets ----
#define WS_CNT   0                         // int[8]
#define WS_CNT2  64                        // int[8]
#define WS_OFF   128                       // int[9]
#define WS_JOBS  192                       // int[1+MAXJOBS]
#define WS_TI    512                       // int[NTOK*2]
#define WS_TW    (WS_TI + NTOK*2*4)        // float[NTOK*2]
#define WS_TOK   (WS_TW + NTOK*2*4)        // int[NROUTED]
#define WS_GWT   (WS_TOK + NROUTED*4)      // float[NROUTED]
#define WS_XG    (((WS_GWT + NROUTED*4) + 255) & ~255)       // bf16[NROUTED][1024]  (16 MB)
#define WS_H     (WS_XG + (size_t)NROUTED*D_MODEL*2)         // bf16[NROUTED][4096]  (64 MB)
#define WS_WT    (WS_H + (size_t)NROUTED*D_FF*2)             // bf16[E][F][K] shared (64 MB)
// total ~144 MB

__device__ __forceinline__ unsigned short f2bf(float f){
  union { float f; unsigned u; } a; a.f = f;
  unsigned u = a.u;
  u = u + 0x7FFF + ((u >> 16) & 1);   // RNE
  return (unsigned short)(u >> 16);
}

__device__ __forceinline__ void gload_lds16(const void* g, void* l){
  __builtin_amdgcn_global_load_lds((const __attribute__((address_space(1))) void*)g,
                                   (__attribute__((address_space(3))) void*)l, 16, 0, 0);
}

// ---------------- gating ----------------
__global__ void moe_gate_kernel(const float* __restrict__ x, const float* __restrict__ gw,
                                int* cnt, int* __restrict__ ti, float* __restrict__ tw){
  int n = blockIdx.x*4 + (threadIdx.x >> 6);
  int lane = threadIdx.x & 63;
  const float* xr = x + (size_t)n * D_MODEL;
  float acc[NEXP];
  #pragma unroll
  for (int e=0;e<NEXP;e++) acc[e] = 0.f;
  for (int d=lane; d<D_MODEL; d+=64){
    float xv = xr[d];
    #pragma unroll
    for (int e=0;e<NEXP;e++) acc[e] += xv * gw[d*NEXP + e];
  }
  #pragma unroll
  for (int e=0;e<NEXP;e++){
    #pragma unroll
    for (int o=32;o;o>>=1) acc[e] += __shfl_down(acc[e], o, 64);
  }
  if (lane == 0){
    int i0 = 0; float v0 = acc[0];
    #pragma unroll
    for (int e=1;e<NEXP;e++) if (acc[e] > v0){ v0 = acc[e]; i0 = e; }
    int i1 = -1; float v1 = -1e30f;
    #pragma unroll
    for (int e=0;e<NEXP;e++) if (e != i0 && acc[e] > v1){ v1 = acc[e]; i1 = e; }
    float p = expf(v1 - v0);
    float inv = 1.f / (1.f + p);
    ti[n*2] = i0; ti[n*2+1] = i1;
    tw[n*2] = inv; tw[n*2+1] = p * inv;
    atomicAdd(&cnt[i0], 1); atomicAdd(&cnt[i1], 1);
  }
}

// prefix sums + job list (job = one 256-row stripe of one expert)
__global__ void moe_prefix_kernel(const int* __restrict__ cnt, int* __restrict__ off,
                                  int* __restrict__ jobs){
  if (threadIdx.x == 0){
    int s = 0;
    for (int e=0;e<NEXP;e++){ off[e] = s; s += cnt[e]; }
    off[NEXP] = s;
    int idx = 0;
    for (int e=0;e<NEXP;e++){
      int ns = (cnt[e] + 255) >> 8;
      for (int q=0;q<ns;q++) jobs[1+idx++] = (e<<16) | q;
    }
    jobs[0] = idx;
  }
}

__global__ void moe_assign_kernel(const float* __restrict__ x, const int* __restrict__ ti,
                                  const float* __restrict__ tw, const int* __restrict__ off,
                                  int* cnt2, int* __restrict__ tok, float* __restrict__ gwt,
                                  unsigned short* __restrict__ Xg){
  __shared__ int ss[2];
  int n = blockIdx.x;
  if (threadIdx.x == 0){
    int i0 = ti[n*2], i1 = ti[n*2+1];
    int s0 = off[i0] + atomicAdd(&cnt2[i0], 1);
    int s1 = off[i1] + atomicAdd(&cnt2[i1], 1);
    tok[s0] = n; tok[s1] = n;
    gwt[s0] = tw[n*2]; gwt[s1] = tw[n*2+1];
    ss[0] = s0; ss[1] = s1;
  }
  __syncthreads();
  int s0 = ss[0], s1 = ss[1];
  int t = threadIdx.x;
  f32x4 v = *(const f32x4*)(x + (size_t)n * D_MODEL + t*4);
  us4 pk = { f2bf(v.x), f2bf(v.y), f2bf(v.z), f2bf(v.w) };
  // NT: written once, consumed by GEMM1 on other XCDs -> don't pollute L2
  __builtin_nontemporal_store(pk, (us4*)(Xg + (size_t)s0 * D_MODEL + t*4));
  __builtin_nontemporal_store(pk, (us4*)(Xg + (size_t)s1 * D_MODEL + t*4));
}

// ---------------- weight transpose + bf16 convert: W(E,K,F) f32 -> Wt(E,F,K) bf16 ----------------
__global__ __launch_bounds__(256) void transpose_bf16_kernel(
    const float* __restrict__ W, unsigned short* __restrict__ Wt, int K, int F){
  __shared__ float tile[64][65];
  int e = blockIdx.z;
  int f0 = blockIdx.x * 64, k0 = blockIdx.y * 64;
  const float* Wb = W + (size_t)e * K * F;
  unsigned short* Wtb = Wt + (size_t)e * F * K;
  int tid = threadIdx.x;
  #pragma unroll
  for (int i=0;i<4;i++){
    int idx = i*256 + tid;
    int r = idx >> 4, c4 = (idx & 15) * 4;
    f32x4 v = __builtin_nontemporal_load((const f32x4*)(Wb + (size_t)(k0 + r) * F + f0 + c4));
    tile[r][c4] = v.x; tile[r][c4+1] = v.y; tile[r][c4+2] = v.z; tile[r][c4+3] = v.w;
  }
  __syncthreads();
  #pragma unroll
  for (int i=0;i<4;i++){
    int idx = i*256 + tid;
    int f = idx >> 4, k4 = (idx & 15) * 4;
    us4 pk = { f2bf(tile[k4][f]), f2bf(tile[k4+1][f]), f2bf(tile[k4+2][f]), f2bf(tile[k4+3][f]) };
    __builtin_nontemporal_store(pk, (us4*)(Wtb + (size_t)(f0 + f) * K + k0 + k4));
  }
}

// ---------------- GEMM: 256x256 tile, BK=32, 16 waves (1024 thr), ring-3 LDS, counted vmcnt ----------------
// MODE 1: Xg@W1t^T -> gelu -> H(NT)   (K=1024, 32 steps; grid.x = 16 col-tiles)
// MODE 2: H@W2t^T *g -> atomic out    (K=4096 split 2-way: grid.x=(kchunk<<2)|col; 64 steps)
// 1 block/CU, 16 waves = 4 contexts/SIMD. LDS ring 3x32KB; vmcnt(2) in-loop (never drains).
// All streaming writes NT -> keep L2 clean for B/A panel reuse (eviction-theory A/B).
template<int MODE>
__global__ __launch_bounds__(1024) void moe_gemm_kernel(
    char* __restrict__ wsb, const unsigned short* __restrict__ Bt,
    const float* __restrict__ bias, float* __restrict__ out)
{
  const int* jobs = (const int*)(wsb + WS_JOBS);
  if ((int)blockIdx.y >= jobs[0]) return;
  const int jb = jobs[1 + blockIdx.y];
  const int e = jb >> 16;
  const int row0 = (jb & 0xffff) << 8;

  const int* off = (const int*)(wsb + WS_OFF);
  const int n0 = off[e];
  const int ne = off[e+1] - n0;

  constexpr int K  = (MODE==1) ? D_MODEL : D_FF;
  constexpr int NT = (MODE==1) ? 32 : 64;         // BK=32 K-steps
  const int bx     = (MODE==1) ? blockIdx.x : (blockIdx.x & 3);
  const int kchunk = (MODE==1) ? 0 : (blockIdx.x >> 2);
  const int n_off  = bx * 256;
  const size_t kcb = (size_t)kchunk * 4096;       // byte offset of 2048-wide K-chunk

  const unsigned short* Ag  = (const unsigned short*)(wsb + (MODE==1 ? (size_t)WS_XG : (size_t)WS_H));
  const unsigned short* Bgt = Bt + (size_t)e * D_FF * D_MODEL;

  __shared__ __align__(16) char lds[3*32768];     // ring: [slot][ A 16KB | B 16KB ]

  const int tid = threadIdx.x, lane = tid & 63, w = tid >> 6;
  const int wr = w >> 2, wc = w & 3;              // 4x4 wave grid; wave tile 64x64

  // ---- staging (2 x gload_lds16 per thread per step) ----
  const int rA   = w*16 + (lane >> 2);            // 0..255
  const int qs   = ((lane & 3) ^ ((rA >> 1) & 3)) << 4;   // pre-swizzled source chunk
  int grA = row0 + rA; if (grA >= ne) grA = ne - 1;
  const char* aSrc = (const char*)(Ag + (size_t)(n0 + grA) * K) + kcb + qs;
  const char* bSrc = (const char*)(Bgt + (size_t)(n_off + rA) * K) + kcb + qs;
  const int dA = w*1024, dB = 16384 + w*1024;     // wave-uniform LDS dests

  // ---- fragment read offsets (2-way bank = free) ----
  const int q0 = lane >> 4;
  int aoff[4], boff[4];
  #pragma unroll
  for (int mi=0; mi<4; mi++){
    int row = wr*64 + mi*16 + (lane & 15);
    aoff[mi] = row*64 + ((q0 ^ ((row>>1)&3)) << 4);
  }
  #pragma unroll
  for (int ni=0; ni<4; ni++){
    int col = wc*64 + ni*16 + (lane & 15);
    boff[ni] = 16384 + col*64 + ((q0 ^ ((col>>1)&3)) << 4);
  }

  f32x4 acc[4][4];
  #pragma unroll
  for (int i=0;i<4;i++)
    #pragma unroll
    for (int j=0;j<4;j++) acc[i][j] = (f32x4){0.f,0.f,0.f,0.f};

  #define STAGE(tt, ss) { \
    gload_lds16(aSrc + (size_t)(tt)*64, lds + (ss)*32768 + dA); \
    gload_lds16(bSrc + (size_t)(tt)*64, lds + (ss)*32768 + dB); }

  STAGE(0, 0);
  STAGE(1, 1);

  for (int t = 0; t < NT; ++t){
    // wait tile t (own newest 2 outstanding = tile t+1 may stay in flight)
    if (t < NT-1) asm volatile("s_waitcnt vmcnt(2)" ::: "memory");
    else          asm volatile("s_waitcnt vmcnt(0)" ::: "memory");
    __builtin_amdgcn_s_barrier();
    __builtin_amdgcn_sched_barrier(0);

    if (t + 2 < NT) STAGE(t + 2, (t + 2) % 3);    // slot free: readers done before this barrier

    const char* base = lds + (t % 3) * 32768;
    bf16x8 a[4], b[4];
    #pragma unroll
    for (int mi=0; mi<4; mi++) a[mi] = *(const bf16x8*)(base + aoff[mi]);
    #pragma unroll
    for (int ni=0; ni<4; ni++) b[ni] = *(const bf16x8*)(base + boff[ni]);

    asm volatile("s_waitcnt lgkmcnt(0)" ::: "memory");
    __builtin_amdgcn_sched_barrier(0);
    __builtin_amdgcn_s_setprio(1);
    #pragma unroll
    for (int ni=0; ni<4; ni++)
      #pragma unroll
      for (int mi=0; mi<4; mi++)
        acc[mi][ni] = __builtin_amdgcn_mfma_f32_16x16x32_bf16(a[mi], b[ni], acc[mi][ni], 0, 0, 0);
    __builtin_amdgcn_s_setprio(0);
    __builtin_amdgcn_sched_barrier(0);
  }
  #undef STAGE

  // ---- epilogue (wave tile 64 x 64) ----
  if (MODE == 1){
    const float* b1 = bias + (size_t)e * D_FF;
    unsigned short* H = (unsigned short*)(wsb + (size_t)WS_H);
    #pragma unroll
    for (int mi=0; mi<4; mi++){
      int rbase = wr*64 + mi*16 + ((lane>>4)<<2);
      #pragma unroll
      for (int rr=0;rr<4;rr++){
        int lrow = rbase + rr;
        if (row0 + lrow < ne){
          size_t hb = (size_t)(n0 + row0 + lrow) * D_FF;
          #pragma unroll
          for (int ni=0; ni<4; ni++){
            int gcol = n_off + wc*64 + ni*16 + (lane&15);
            float v = acc[mi][ni][rr] + b1[gcol];
            v = 0.5f * v * (1.f + erff(v * 0.70710678118654752f));
            __builtin_nontemporal_store(f2bf(v), H + hb + gcol);   // NT: consumed cross-XCD
          }
        }
      }
    }
  } else {
    const float* b2 = bias + (size_t)e * D_MODEL;
    const int* tok = (const int*)(wsb + WS_TOK);
    const float* gwt = (const float*)(wsb + WS_GWT);
    #pragma unroll
    for (int mi=0; mi<4; mi++){
      int rbase = wr*64 + mi*16 + ((lane>>4)<<2);
      #pragma unroll
      for (int rr=0;rr<4;rr++){
        int lrow = rbase + rr;
        if (row0 + lrow < ne){
          int slot = n0 + row0 + lrow;
          int tk = tok[slot];
          float g = gwt[slot];
          float* orow = out + (size_t)tk * D_MODEL;
          #pragma unroll
          for (int ni=0; ni<4; ni++){
            int gcol = n_off + wc*64 + ni*16 + (lane&15);
            float bb = (kchunk == 0) ? b2[gcol] : 0.f;
            atomicAdd(orow + gcol, (acc[mi][ni][rr] + bb) * g);
          }
        }
      }
    }
  }
}

extern "C" void kernel_launch(void* const* d_in, const int* in_sizes, int n_in,
                              void* d_out, int out_size, void* d_ws, size_t ws_size,
                              hipStream_t stream){
  const float* x   = (const float*)d_in[0];
  const float* gw  = (const float*)d_in[1];
  const float* w1  = (const float*)d_in[2];
  const float* b1  = (const float*)d_in[3];
  const float* w2  = (const float*)d_in[4];
  const float* b2  = (const float*)d_in[5];
  float* out = (float*)d_out;
  char* ws = (char*)d_ws;
  unsigned short* Wt = (unsigned short*)(ws + (size_t)WS_WT);

  hipMemsetAsync(ws, 0, 512, stream);                                   // counters + jobs
  hipMemsetAsync(out, 0, (size_t)NTOK * D_MODEL * sizeof(float), stream);

  moe_gate_kernel<<<NTOK/4, 256, 0, stream>>>(x, gw, (int*)(ws+WS_CNT),
                                              (int*)(ws+WS_TI), (float*)(ws+WS_TW));
  moe_prefix_kernel<<<1, 64, 0, stream>>>((const int*)(ws+WS_CNT), (int*)(ws+WS_OFF),
                                          (int*)(ws+WS_JOBS));
  moe_assign_kernel<<<NTOK, 256, 0, stream>>>(x, (const int*)(ws+WS_TI),
                                              (const float*)(ws+WS_TW), (const int*)(ws+WS_OFF),
                                              (int*)(ws+WS_CNT2), (int*)(ws+WS_TOK),
                                              (float*)(ws+WS_GWT),
                                              (unsigned short*)(ws + (size_t)WS_XG));
  // W1 (E,1024,4096) f32 -> Wt (E,4096,1024) bf16 ; then GEMM1
  transpose_bf16_kernel<<<dim3(D_FF/64, D_MODEL/64, NEXP), 256, 0, stream>>>(w1, Wt, D_MODEL, D_FF);
  moe_gemm_kernel<1><<<dim3(D_FF/256, MAXJOBS), 1024, 0, stream>>>(ws, Wt, b1, out);
  // W2 (E,4096,1024) f32 -> Wt (E,1024,4096) bf16 ; then GEMM2 (K split 2-way)
  transpose_bf16_kernel<<<dim3(D_MODEL/64, D_FF/64, NEXP), 256, 0, stream>>>(w2, Wt, D_FF, D_MODEL);
  moe_gemm_kernel<2><<<dim3((D_MODEL/256)*2, MAXJOBS), 1024, 0, stream>>>(ws, Wt, b2, out);
}